// Round 14
// baseline (270.230 us; speedup 1.0000x reference)
//
#include <hip/hip_runtime.h>
#include <hip/hip_bf16.h>

typedef unsigned short u16;
typedef float f32x4 __attribute__((ext_vector_type(4)));
typedef __bf16 bf16x8 __attribute__((ext_vector_type(8)));
typedef unsigned short su8v __attribute__((ext_vector_type(8)));
typedef unsigned short su4v __attribute__((ext_vector_type(4)));

#define BB 8
#define NHD 8
#define DD 128
#define NN 1024
#define DIM 1024
#define H3 3072
#define MM 8192
// scale * log2(e), folded into Q weights so softmax is exp2(raw dot)
#define QSC (0.08838834764831845f * 1.4426950408889634f)

__constant__ int   d_IDX[16] = {0,1,2,3, 1,0,3,2, 2,3,0,1, 3,2,1,0};
__constant__ float d_SGN[16] = {1.f,-1.f,-1.f,-1.f, 1.f,1.f,1.f,-1.f,
                                1.f,-1.f,1.f,1.f,  1.f,1.f,-1.f,1.f};

__device__ __forceinline__ f32x4 mfma16(su8v a, su8v b, f32x4 c) {
  return __builtin_amdgcn_mfma_f32_16x16x32_bf16(
      __builtin_bit_cast(bf16x8, a), __builtin_bit_cast(bf16x8, b), c, 0, 0, 0);
}
__device__ __forceinline__ u16 f2b(float f) {  // RNE
  unsigned int u = __builtin_bit_cast(unsigned int, f);
  u += 0x7fffu + ((u >> 16) & 1u);
  return (u16)(u >> 16);
}
__device__ __forceinline__ float b2f(u16 v) {
  unsigned int u = ((unsigned int)v) << 16;
  return __builtin_bit_cast(float, u);
}
typedef const __attribute__((address_space(1))) unsigned int* gas_t;
typedef __attribute__((address_space(3))) unsigned int* las_t;
__device__ __forceinline__ void gll16(const u16* g, u16* l) {
  __builtin_amdgcn_global_load_lds((gas_t)g, (las_t)l, 16, 0, 0);
}

// ---------------------------------------------------------------------------
// prep_weff: effective weights [out_row][in_col] bf16; Q-rows pre-scaled by QSC
// ---------------------------------------------------------------------------
__global__ __launch_bounds__(256) void prep_weff(
    const float* __restrict__ wqkv, const float* __restrict__ wproj,
    u16* __restrict__ weffQ, u16* __restrict__ weffP) {
  int tid = blockIdx.x * 256 + threadIdx.x;
  int stride = gridDim.x * 256;
  for (int i = tid; i < H3 * DIM; i += stride) {
    int row = i >> 10, col = i & 1023;
    int q = row / 768, o = row - q * 768;
    int p = col >> 8, c = col & 255;
    float v = d_SGN[q * 4 + p] * wqkv[(d_IDX[q * 4 + p] * 768 + o) * 256 + c];
    if (o < 256) v *= QSC;  // Q rows
    weffQ[i] = f2b(v);
  }
  for (int i = tid; i < DIM * DIM; i += stride) {
    int row = i >> 10, col = i & 1023;
    int q = row >> 8, o = row & 255;
    int p = col >> 8, c = col & 255;
    weffP[i] = f2b(d_SGN[q * 4 + p] * wproj[(d_IDX[q * 4 + p] * 256 + o) * 256 + c]);
  }
}

// ---------------------------------------------------------------------------
// prep_x: x (B,Cc,4,N) fp32 -> Ax bf16 [8192 (b,n)][1024 (p,c)].
// LDS transpose, layout T[n][pc] stride 264 u16 (16B-aligned su8v reads).
// ---------------------------------------------------------------------------
__global__ __launch_bounds__(256) void prep_x(
    const float* __restrict__ x, u16* __restrict__ Ax) {
  __shared__ u16 T[64 * 264];  // [n][pc], stride 264
  int blk = blockIdx.x;
  int nc = blk & 15;
  int cc = (blk >> 4) & 3;
  int b = blk >> 6;
  int n0 = nc * 64, c0 = cc * 64;
  int tid = threadIdx.x;
  int nseg = tid & 15, rq = tid >> 4;  // rq 0..15
#pragma unroll
  for (int pass = 0; pass < 16; ++pass) {
    int rr = pass * 16 + rq;  // pc local 0..255: p = rr>>6, c = rr&63
    int p = rr >> 6, c = rr & 63;
    float4 f = *(const float4*)(x + (((size_t)(b * 256 + c0 + c)) * 4 + p) * 1024 +
                                n0 + nseg * 4);
    T[(nseg * 4 + 0) * 264 + rr] = f2b(f.x);
    T[(nseg * 4 + 1) * 264 + rr] = f2b(f.y);
    T[(nseg * 4 + 2) * 264 + rr] = f2b(f.z);
    T[(nseg * 4 + 3) * 264 + rr] = f2b(f.w);
  }
  __syncthreads();
  int nl = tid >> 5, lc = tid & 31;
#pragma unroll
  for (int pass = 0; pass < 8; ++pass) {
    int n = pass * 8 + nl;
    su8v v = *(const su8v*)(&T[n * 264 + lc * 8]);
    int pcl = lc * 8;
    *(su8v*)(Ax + (size_t)(b * 1024 + n0 + n) * 1024 + (pcl >> 6) * 256 + c0 +
             (pcl & 63)) = v;
  }
}

// ---------------------------------------------------------------------------
// 8-wave GEMM core, 256x256 block tile, wave tile 128x64 (2x4 wave grid),
// BK=32, 3-slot ring = 96 KB (1 block/CU, 2 waves/SIMD). Round-13 A/B showed
// occupancy beyond 2 waves/SIMD doesn't lift MfmaUtil — the binder is
// DS-pipe bytes per MFMA. Wave tile 128x64 raises arithmetic intensity
// M*N/(M+N): 32 -> 42.7 FLOP per LDS byte (-25% frag-read traffic/MFMA).
// ONE barrier per K-tile + counted vmcnt(4) (4 gll/wave/tile, 2 tiles in
// flight). LDS rows 32 u16 = 4 x 16B blocks; swizzle key (row>>1)&3:
// write slot (lane&3)^((srow>>1)&3), read slot quad^((l16>>1)&3) ->
// all accesses 2-way max (free; measured 0 conflicts in round 13).
// ---------------------------------------------------------------------------
__device__ __forceinline__ void gemm_core256(
    const u16* __restrict__ Ag, const u16* __restrict__ Bg,
    u16* As, u16* Bs, int tid, f32x4 (&acc)[8][4]) {
  constexpr int NT = 32;  // K = 1024 / BK(32)
  int w = tid >> 6, lane = tid & 63, l16 = lane & 15, quad = lane >> 4;
  int wm = w >> 2, wn = w & 3;
  int sx = (l16 >> 1) & 3;
  int srow = lane >> 2;               // 0..15 within staged 16-row group
  int sblk = (lane & 3) ^ ((srow >> 1) & 3);

  auto STAGE = [&](int tt, int bs) {
#pragma unroll
    for (int c = 0; c < 2; ++c) {
      int r0 = (c * 8 + w) * 16;      // wave-uniform row base
      gll16(Ag + (size_t)(r0 + srow) * 1024 + tt * 32 + sblk * 8,
            As + (size_t)bs * (256 * 32) + r0 * 32);
      gll16(Bg + (size_t)(r0 + srow) * 1024 + tt * 32 + sblk * 8,
            Bs + (size_t)bs * (256 * 32) + r0 * 32);
    }
  };

  STAGE(0, 0);
  STAGE(1, 1);
  asm volatile("s_waitcnt vmcnt(4)" ::: "memory");
  __builtin_amdgcn_s_barrier();

  int cur = 0, nxt = 1, stg = 2;
  for (int t = 0; t < NT; ++t) {
    const u16* At = As + (size_t)cur * (256 * 32);
    const u16* Bt = Bs + (size_t)cur * (256 * 32);
    su8v af[8], bf[4];
#pragma unroll
    for (int i = 0; i < 8; ++i)
      af[i] = *(const su8v*)(At + (wm * 128 + i * 16 + l16) * 32 +
                             ((quad ^ sx) * 8));
#pragma unroll
    for (int j = 0; j < 4; ++j)
      bf[j] = *(const su8v*)(Bt + (wn * 64 + j * 16 + l16) * 32 +
                             ((quad ^ sx) * 8));
    if (t + 2 < NT) STAGE(t + 2, stg);
    __builtin_amdgcn_s_setprio(1);
#pragma unroll
    for (int i = 0; i < 8; ++i)
#pragma unroll
      for (int j = 0; j < 4; ++j)
        acc[i][j] = mfma16(af[i], bf[j], acc[i][j]);
    __builtin_amdgcn_s_setprio(0);
    if (t < NT - 2)       asm volatile("s_waitcnt vmcnt(4)" ::: "memory");
    else if (t == NT - 2) asm volatile("s_waitcnt vmcnt(0)" ::: "memory");
    if (t < NT - 1) {
      asm volatile("" ::: "memory");
      __builtin_amdgcn_s_barrier();
      asm volatile("" ::: "memory");
    }
    int tmp = cur; cur = nxt; nxt = stg; stg = tmp;
  }
}

// ---------------------------------------------------------------------------
// QKV GEMM: tile = 256 (bn) x 256 (chan). Grid 32x12 = 384 blocks. Each
// 256-chan block is one of Q/K/V (off in {0,256,512}) spanning TWO heads;
// head = 2q + (dl>>7), d = dl&127 computed per element.
// V store: 4-key halves of each 8-key group swapped when (d&2) (npos^4) so
// attn's bijective Vt granule swizzle sees key-linear 16B blocks.
// ---------------------------------------------------------------------------
__global__ __launch_bounds__(512) void gemm_qkv_mfma(
    const u16* __restrict__ Ax, const u16* __restrict__ weffQ,
    const float* __restrict__ bqkv,
    u16* __restrict__ Qb, u16* __restrict__ Kb, u16* __restrict__ VbT) {
  __shared__ u16 smem[3 * 512 * 32];  // 96 KB: 3-slot ring, A + B halves
  int bn0 = blockIdx.x * 256;
  int col0 = blockIdx.y * 256;
  int q = col0 / 768;
  int off = col0 - q * 768;   // 0, 256, 512
  int sel = off >> 8;         // 0=Q 1=K 2=V (uniform per block)
  int tid = threadIdx.x;
  int w = tid >> 6, lane = tid & 63, l16 = lane & 15, quad = lane >> 4;
  int wm = w >> 2, wn = w & 3;
  f32x4 acc[8][4];
#pragma unroll
  for (int i = 0; i < 8; ++i)
#pragma unroll
    for (int j = 0; j < 4; ++j) acc[i][j] = (f32x4){0.f, 0.f, 0.f, 0.f};

  if (sel == 2) {
    // ---- V: m=bn (256), n=chan (256) ----
    gemm_core256(Ax + (size_t)bn0 * 1024, weffQ + (size_t)col0 * 1024,
                 smem, smem + 3 * 256 * 32, tid, acc);
#pragma unroll
    for (int j = 0; j < 4; ++j) {
      int dl = wn * 64 + j * 16 + l16;   // 0..255 within block
      int head = q * 2 + (dl >> 7);
      int d = dl & 127;
      float bias = bqkv[col0 + dl];
      int hswap = (d & 2) << 1;  // swap 4-key halves when d bit1 set
#pragma unroll
      for (int i = 0; i < 8; ++i) {
        int m = bn0 + wm * 128 + i * 16 + quad * 4;
        int b = m >> 10, npos = m & 1023;
        int bh = b * NHD + head;
        su4v pk;
#pragma unroll
        for (int r = 0; r < 4; ++r) pk[r] = f2b(acc[i][j][r] + bias);
        *(su4v*)(VbT + ((size_t)bh * DD + d) * NN + (npos ^ hswap)) = pk;
      }
    }
  } else {
    // ---- Q/K: m=chan (256), n=bn (256) ----
    gemm_core256(weffQ + (size_t)col0 * 1024, Ax + (size_t)bn0 * 1024,
                 smem, smem + 3 * 256 * 32, tid, acc);
    u16* dst = (sel == 0) ? Qb : Kb;
    float sc = (sel == 0) ? (float)QSC : 1.0f;
#pragma unroll
    for (int i = 0; i < 8; ++i) {
      int mmb = wm * 128 + i * 16 + quad * 4;  // dl base, r contiguous
      int head = q * 2 + (mmb >> 7);
      int dbase = mmb & 127;
      float4 b4 = *(const float4*)(bqkv + col0 + mmb);
#pragma unroll
      for (int j = 0; j < 4; ++j) {
        int n = bn0 + wn * 64 + j * 16 + l16;
        int b = n >> 10, npos = n & 1023;
        int bh = b * NHD + head;
        su4v pk;
        pk[0] = f2b(acc[i][j][0] + b4.x * sc);
        pk[1] = f2b(acc[i][j][1] + b4.y * sc);
        pk[2] = f2b(acc[i][j][2] + b4.z * sc);
        pk[3] = f2b(acc[i][j][3] + b4.w * sc);
        *(su4v*)(dst + ((size_t)bh * NN + npos) * DD + dbase) = pk;
      }
    }
  }
}

// ---------------------------------------------------------------------------
// Flash attention, FULL-K (no split, no merge kernel): 512 blocks =
// qt(8) x bh(64, low bits -> same-bh blocks share XCD for K/V L2 reuse).
// 128 q x 1024 keys per block, KVBLK=32 -> 32 K-tiles, 3-slot LDS ring,
// STAGE(kt+2) at top of kt, counted vmcnt(4) + ONE barrier per tile.
// In-register P; PV + rowsum at K=32: the two 16-key P slices concatenate
// into one K=32 A-fragment and the matching V B-fragment is the concat of
// the same two b64 granule reads (round 12: halved PV MFMA issue count).
// accL[mi][r] = FULL row-sum for the q-rows this lane owns in accO ->
// normalize in-register, write final AO directly (no OP/LS round trip).
// Bank layout (conflict-free, measured 0 in rounds 11/12):
//  - Ks rows 256B = 16 blocks, slot = blk ^ (key&15).
//  - Vt rows 64B = 8 granules of 4 keys; granule slot = nat ^ (l16>>1 key);
//    odd keys need 16B-block atomicity fix: V stored globally with 4-key
//    halves swapped when d&2 (gemm_qkv), staged with block key (dv>>2)&3.
// No launch_bounds min-waves (rounds 6/7: caps below natural regs => spill).
// ---------------------------------------------------------------------------
__global__ __launch_bounds__(256) void attn_mfma(
    const u16* __restrict__ Qb, const u16* __restrict__ Kb,
    const u16* __restrict__ VbT, u16* __restrict__ AO) {
  __shared__ u16 Ks[3 * 32 * 128];  // 24 KB ring, 4-bit xor-swizzled blocks
  __shared__ u16 Vt[3 * 128 * 32];  // 24 KB ring, bijective granule swizzle
  int blk = blockIdx.x;
  int bh = blk & 63;
  int qt = blk >> 6;
  int n0 = qt * 128;
  int tid = threadIdx.x;
  int w = tid >> 6, lane = tid & 63, l16 = lane & 15, quad = lane >> 4;
  const u16* Qg = Qb + ((size_t)bh * NN + n0) * DD;
  const u16* Kg = Kb + (size_t)bh * NN * DD;
  const u16* Vg = VbT + (size_t)bh * DD * NN;
  int s7 = l16 >> 1;  // Vt granule swizzle key

  auto STAGE = [&](int kt, int s) {
    int c0 = kt * 32;
#pragma unroll
    for (int t = 0; t < 2; ++t) {
      int ci = w * 2 + t;  // 0..7
      // K: 1KB = 4 rows x 256B; block slot holds global blk^(key&15)
      int krow = ci * 4 + (lane >> 4);
      int kblk = (lane & 15) ^ (krow & 15);
      gll16(Kg + (size_t)(c0 + krow) * DD + kblk * 8, Ks + s * 4096 + ci * 512);
      // V: 1KB = 16 rows x 64B; 16B block slot = nat ^ ((dv>>2)&3); the
      // within-block half order comes pre-swapped from global when dv&2
      int dv = ci * 16 + (lane >> 2);
      int vblk = (lane & 3) ^ ((dv >> 2) & 3);
      gll16(Vg + (size_t)dv * NN + c0 + vblk * 8, Vt + s * 4096 + ci * 512);
    }
  };

  su8v qreg[2][4];  // B-fragment: n=q (l16), k=d
#pragma unroll
  for (int mi = 0; mi < 2; ++mi)
#pragma unroll
    for (int ch = 0; ch < 4; ++ch)
      qreg[mi][ch] = *(const su8v*)(Qg + (size_t)(w * 32 + mi * 16 + l16) * DD +
                                    ch * 32 + quad * 8);

  su8v ones8;
#pragma unroll
  for (int e = 0; e < 8; ++e) ones8[e] = 0x3F80;
  f32x4 accL[2];
  accL[0] = (f32x4){0.f, 0.f, 0.f, 0.f};
  accL[1] = (f32x4){0.f, 0.f, 0.f, 0.f};
  f32x4 accO[2][8];
#pragma unroll
  for (int mi = 0; mi < 2; ++mi)
#pragma unroll
    for (int dt = 0; dt < 8; ++dt) accO[mi][dt] = (f32x4){0.f, 0.f, 0.f, 0.f};

  STAGE(0, 0); STAGE(1, 1);
  asm volatile("s_waitcnt vmcnt(4)" ::: "memory");
  __builtin_amdgcn_s_barrier();

  int cur = 0, nxt = 1, stg = 2;
  for (int kt = 0; kt < 32; ++kt) {
    const u16* Kc = Ks + cur * 4096;
    const u16* Vc = Vt + cur * 4096;
    if (kt + 2 < 32) STAGE(kt + 2, stg);

    // QK^T for both 16-key slices -> packed P (kept per slice)
    su4v pk[2][2];  // [mi][j]
#pragma unroll
    for (int j = 0; j < 2; ++j) {
      f32x4 s0 = (f32x4){0.f, 0.f, 0.f, 0.f};
      f32x4 s1 = (f32x4){0.f, 0.f, 0.f, 0.f};
#pragma unroll
      for (int ch = 0; ch < 4; ++ch) {
        su8v kf = *(const su8v*)(Kc + (j * 16 + l16) * 128 +
                                 (((ch * 4 + quad) ^ l16) * 8));
        s0 = mfma16(kf, qreg[0][ch], s0);
        s1 = mfma16(kf, qreg[1][ch], s1);
      }
      su4v p0, p1;
#pragma unroll
      for (int r = 0; r < 4; ++r) {
        float pa = __builtin_exp2f(s0[r]);
        p0[r] = (u16)(__builtin_bit_cast(unsigned int, pa) >> 16);
        float pb = __builtin_exp2f(s1[r]);
        p1[r] = (u16)(__builtin_bit_cast(unsigned int, pb) >> 16);
      }
      pk[0][j] = p0;
      pk[1][j] = p1;
    }
    // concat the two slices -> K=32 A-fragments
    su8v p80, p81;
#pragma unroll
    for (int e = 0; e < 4; ++e) {
      p80[e] = pk[0][0][e]; p80[4 + e] = pk[0][1][e];
      p81[e] = pk[1][0][e]; p81[4 + e] = pk[1][1][e];
    }
    accL[0] = mfma16(p80, ones8, accL[0]);
    accL[1] = mfma16(p81, ones8, accL[1]);
    // PV at K=32: B-fragment = concat of the j0/j1 granule reads
#pragma unroll
    for (int dt = 0; dt < 8; ++dt) {
      const u16* vrow = Vc + (dt * 16 + l16) * 32;
      su4v va = *(const su4v*)(vrow + ((quad ^ s7) * 4));
      su4v vb = *(const su4v*)(vrow + (((4 + quad) ^ s7) * 4));
      su8v v8;
#pragma unroll
      for (int e = 0; e < 4; ++e) { v8[e] = va[e]; v8[4 + e] = vb[e]; }
      accO[0][dt] = mfma16(p80, v8, accO[0][dt]);
      accO[1][dt] = mfma16(p81, v8, accO[1][dt]);
    }

    if (kt < 30)       asm volatile("s_waitcnt vmcnt(4)" ::: "memory");
    else if (kt == 30) asm volatile("s_waitcnt vmcnt(0)" ::: "memory");
    if (kt < 31) {
      asm volatile("" ::: "memory");
      __builtin_amdgcn_s_barrier();
      asm volatile("" ::: "memory");
    }
    int tmp = cur; cur = nxt; nxt = stg; stg = tmp;
  }

  // normalize in-register and write final AO[b*1024+n][head*128+d]
  int bb = bh >> 3, head = bh & 7;
#pragma unroll
  for (int mi = 0; mi < 2; ++mi) {
#pragma unroll
    for (int r = 0; r < 4; ++r) {
      int row = w * 32 + mi * 16 + quad * 4 + r;
      float iv = 1.0f / accL[mi][r];
      size_t base = ((size_t)(bb * 1024) + n0 + row) * 1024 + head * 128;
#pragma unroll
      for (int dt = 0; dt < 8; ++dt)
        AO[base + dt * 16 + l16] = f2b(accO[mi][dt][r] * iv);
    }
  }
}

// ---------------------------------------------------------------------------
// quaternion depthwise 3x3 conv (fp32) — writes PE term into workspace
// ---------------------------------------------------------------------------
__global__ __launch_bounds__(256) void qdwconv_kernel(
    const float* __restrict__ x, const float* __restrict__ wpe,
    const float* __restrict__ bpe, float* __restrict__ pe) {
  int blk = blockIdx.x;
  int co = blk & 255;
  int b = blk >> 8;
  __shared__ float pl[4][34 * 34];
  __shared__ float wsm[4][9];
  int tid = threadIdx.x;
  for (int i = tid; i < 4 * 34 * 34; i += 256) ((float*)pl)[i] = 0.f;
  if (tid < 36) wsm[tid / 9][tid % 9] = wpe[((tid / 9) * 256 + co) * 9 + tid % 9];
  __syncthreads();
  for (int i = tid; i < 4 * 1024; i += 256) {
    int p = i >> 10, n = i & 1023;
    int h = n >> 5, ww = n & 31;
    pl[p][(h + 1) * 34 + (ww + 1)] =
        x[(((size_t)b * 256 + co) * 4 + p) * 1024 + n];
  }
  __syncthreads();
  for (int n = tid; n < 1024; n += 256) {
    int h = n >> 5, ww = n & 31;
    float in[4][9];
#pragma unroll
    for (int p = 0; p < 4; ++p)
#pragma unroll
      for (int t = 0; t < 9; ++t)
        in[p][t] = pl[p][(h + t / 3) * 34 + (ww + t % 3)];
#pragma unroll
    for (int q = 0; q < 4; ++q) {
      float acc = bpe[q * 256 + co];
#pragma unroll
      for (int p = 0; p < 4; ++p) {
        int idx = d_IDX[q * 4 + p];
        float s = d_SGN[q * 4 + p];
        float sub = 0.f;
#pragma unroll
        for (int t = 0; t < 9; ++t) sub += in[p][t] * wsm[idx][t];
        acc += s * sub;
      }
      pe[(((size_t)b * 256 + co) * 4 + q) * 1024 + n] = acc;
    }
  }
}

// ---------------------------------------------------------------------------
// proj GEMM: tile = 256 (bn) x 256 (q,o). Grid 32x4 = 128 blocks.
// ---------------------------------------------------------------------------
__global__ __launch_bounds__(512) void gemm_proj_mfma(
    const u16* __restrict__ AO, const u16* __restrict__ weffP,
    const float* __restrict__ bproj, const float* __restrict__ pe,
    float* __restrict__ out) {
  __shared__ u16 smem[3 * 512 * 32];  // 96 KB ring
  int n0 = blockIdx.x * 256;
  int m0 = blockIdx.y * 256;
  int tid = threadIdx.x;
  f32x4 acc[8][4];
#pragma unroll
  for (int i = 0; i < 8; ++i)
#pragma unroll
    for (int j = 0; j < 4; ++j) acc[i][j] = (f32x4){0.f, 0.f, 0.f, 0.f};
  gemm_core256(weffP + (size_t)m0 * 1024, AO + (size_t)n0 * 1024,
               smem, smem + 3 * 256 * 32, tid, acc);

  int w = tid >> 6, lane = tid & 63, l16 = lane & 15, quad = lane >> 4;
  int wm = w >> 2, wn = w & 3;
#pragma unroll
  for (int i = 0; i < 8; ++i) {
#pragma unroll
    for (int r = 0; r < 4; ++r) {
      int mrow = m0 + wm * 128 + i * 16 + quad * 4 + r;
      int q = mrow >> 8, o = mrow & 255;
      float bias = bproj[mrow];
#pragma unroll
      for (int j = 0; j < 4; ++j) {
        int n = n0 + wn * 64 + j * 16 + l16;
        int b = n >> 10, npos = n & 1023;
        size_t oidx = (((size_t)b * 256 + o) * 4 + q) * 1024 + npos;
        out[oidx] = pe[oidx] + acc[i][j][r] + bias;
      }
    }
  }
}

// ---------------------------------------------------------------------------
extern "C" void kernel_launch(void* const* d_in, const int* in_sizes, int n_in,
                              void* d_out, int out_size, void* d_ws,
                              size_t ws_size, hipStream_t stream) {
  const float* x      = (const float*)d_in[0];
  const float* w_qkv  = (const float*)d_in[1];
  const float* b_qkv  = (const float*)d_in[2];
  const float* w_proj = (const float*)d_in[3];
  const float* b_proj = (const float*)d_in[4];
  const float* w_pe   = (const float*)d_in[5];
  const float* b_pe   = (const float*)d_in[6];
  float* out = (float*)d_out;

  u16* ws = (u16*)d_ws;
  u16* weffQ = ws;                                   // 3072*1024
  u16* weffP = weffQ + (size_t)H3 * DIM;             // 1024*1024
  u16* Ax    = weffP + (size_t)DIM * DIM;            // 8192*1024
  u16* Qb    = Ax + (size_t)MM * DIM;                // 64*1024*128
  u16* Kb    = Qb + (size_t)BB * NHD * NN * DD;      // 64*1024*128
  u16* VbT   = Kb + (size_t)BB * NHD * NN * DD;      // 64*128*1024
  u16* AO    = VbT + (size_t)BB * NHD * DD * NN;     // 8192*1024
  float* PE  = (float*)(AO + (size_t)MM * DIM);      // 8192*1024 fp32

  hipLaunchKernelGGL(prep_weff, dim3(4096), dim3(256), 0, stream,
                     w_qkv, w_proj, weffQ, weffP);
  hipLaunchKernelGGL(prep_x, dim3(512), dim3(256), 0, stream, x, Ax);
  hipLaunchKernelGGL(gemm_qkv_mfma, dim3(MM / 256, H3 / 256), dim3(512), 0,
                     stream, Ax, weffQ, b_qkv, Qb, Kb, VbT);
  hipLaunchKernelGGL(attn_mfma, dim3(512), dim3(256), 0, stream,
                     Qb, Kb, VbT, AO);
  hipLaunchKernelGGL(qdwconv_kernel, dim3(BB * 256), dim3(256), 0, stream,
                     x, w_pe, b_pe, PE);
  hipLaunchKernelGGL(gemm_proj_mfma, dim3(MM / 256, DIM / 256), dim3(512), 0,
                     stream, AO, weffP, b_proj, PE, out);
}